// Round 17
// baseline (941.890 us; speedup 1.0000x reference)
//
#include <hip/hip_runtime.h>
#include <cmath>

#define TBUF 1024
#define RCH  256

typedef __bf16 bf16x8 __attribute__((ext_vector_type(8)));
typedef float  f32x4  __attribute__((ext_vector_type(4)));

__device__ inline unsigned short f2bf(float f) {
  unsigned u = __builtin_bit_cast(unsigned, f);
  u += 0x7FFFu + ((u >> 16) & 1u);
  return (unsigned short)(u >> 16);
}
__device__ inline float bf2f(unsigned short h) {
  unsigned u = ((unsigned)h) << 16;
  return __builtin_bit_cast(float, u);
}
__device__ __forceinline__ void gl2lds(const unsigned short* g, void* l) {
  __builtin_amdgcn_global_load_lds(
      (const __attribute__((address_space(1))) unsigned int*)g,
      (__attribute__((address_space(3))) unsigned int*)l, 16, 0, 0);
}

// ---------------- merged weight transforms (one dispatch) ----------------
__global__ __launch_bounds__(256) void prep(
    const float* __restrict__ wf, const float* __restrict__ wg,
    const float* __restrict__ wr, const float* __restrict__ wsk,
    const float* __restrict__ w_in,
    unsigned short* __restrict__ Wb, unsigned short* __restrict__ Wrb,
    float* __restrict__ wskT, float* __restrict__ w2)
{
  const int bid = blockIdx.x;
  const int tid = threadIdx.x;
  if (bid < 16384) {
    int idx = bid * 256 + tid;
    int c  = idx & 255;
    int op = (idx >> 8) & 511;
    int i  = idx >> 17;
    int o  = op & 255;
    const float* src = (op < 256) ? wf : wg;
    const float2 v = *(const float2*)&src[(((size_t)i * 256 + o) * 256 + c) << 1];
    unsigned short* dst = Wb + ((size_t)i * 512 + op) * 512;
    dst[c]       = f2bf(v.y);   // current tap (k=1)
    dst[256 + c] = f2bf(v.x);   // previous tap (k=0)
  } else if (bid < 18432) {
    int idx = (bid - 16384) * 256 + tid;
    float4 v = ((const float4*)wr)[idx];
    uint2 o;
    o.x = (unsigned)f2bf(v.x) | ((unsigned)f2bf(v.y) << 16);
    o.y = (unsigned)f2bf(v.z) | ((unsigned)f2bf(v.w) << 16);
    ((uint2*)Wrb)[idx] = o;
  } else if (bid < 22528) {
    int idx = (bid - 18432) * 256 + tid;
    int s = idx & 127;
    int c = (idx >> 7) & 255;
    int i = idx >> 15;
    wskT[idx] = wsk[(i * 128 + s) * 256 + c];
  } else {
    int idx = (bid - 22528) * 256 + tid;
    int r = idx & 255;
    int fk = idx >> 8;
    int f = fk & 31, k = fk >> 5;
    w2[idx] = w_in[r * 64 + f * 2 + k];
  }
}

// ---------------- input conv (F=32 -> R=256, K=2, d=1) ----------------
__global__ __launch_bounds__(256) void in_conv(
    const float* __restrict__ X, const float* __restrict__ w2,
    const float* __restrict__ b_in, unsigned short* __restrict__ xbb,
    unsigned short* __restrict__ xlo)
{
  const int bid   = blockIdx.x;
  const int b     = bid & 15;
  const int chunk = bid >> 4;
  const int r     = threadIdx.x;
  __shared__ float Xs[17][32];
  const int tt0 = chunk << 4;
  const int t0  = tt0 + 1024;
  for (int idx = r; idx < 17 * 32; idx += 256) {
    int row = idx >> 5, f = idx & 31;
    Xs[row][f] = X[((size_t)b * 2048 + (t0 - 1 + row)) * 32 + f];
  }
  __syncthreads();
  float w0[32], w1[32];
  #pragma unroll
  for (int f = 0; f < 32; ++f) {
    w0[f] = w2[f * 256 + r];
    w1[f] = w2[(32 + f) * 256 + r];
  }
  const float bias = b_in[r];
  float4 prev[8], cur[8];
  #pragma unroll
  for (int q = 0; q < 8; ++q) prev[q] = *(const float4*)&Xs[0][q * 4];
  #pragma unroll
  for (int j = 0; j < 16; ++j) {
    #pragma unroll
    for (int q = 0; q < 8; ++q) cur[q] = *(const float4*)&Xs[j + 1][q * 4];
    float a = bias;
    #pragma unroll
    for (int q = 0; q < 8; ++q) {
      a = fmaf(w0[q*4+0], prev[q].x, a); a = fmaf(w1[q*4+0], cur[q].x, a);
      a = fmaf(w0[q*4+1], prev[q].y, a); a = fmaf(w1[q*4+1], cur[q].y, a);
      a = fmaf(w0[q*4+2], prev[q].z, a); a = fmaf(w1[q*4+2], cur[q].z, a);
      a = fmaf(w0[q*4+3], prev[q].w, a); a = fmaf(w1[q*4+3], cur[q].w, a);
    }
    int tt = tt0 + j;
    size_t off = ((size_t)b * TBUF + tt) * RCH + r;
    if (tt < 3) { xbb[off] = 0; xlo[off] = 0; }
    else {
      unsigned short hn = f2bf(a);
      xbb[off] = hn;
      xlo[off] = f2bf(a - bf2f(hn));
    }
    #pragma unroll
    for (int q = 0; q < 8; ++q) prev[q] = cur[q];
  }
}

// ---------------- single fused layer (r16 champion, unchanged) ----------------
template<int NM>
__global__ __launch_bounds__(1024, 4) void layer_fused(
    const unsigned short* __restrict__ xbb_r, unsigned short* __restrict__ xbb_w,
    unsigned short* __restrict__ xlo,
    const unsigned short* __restrict__ Wb,   // [512][512] bf16
    const unsigned short* __restrict__ Wrb,  // [256][256] bf16
    const float* __restrict__ bF, const float* __restrict__ bG,
    const float* __restrict__ bR,
    int dd, int t_lo, float* __restrict__ fxs_i)
{
  __shared__ __align__(16) unsigned short As[NM * 16 * 520];  // z aliases
  const int bid  = blockIdx.x;
  const int b    = bid & 15;
  const int tile = bid >> 4;
  const int tid  = threadIdx.x;
  const int w    = tid >> 6;          // 0..15
  const int lane = tid & 63;
  const int l15  = lane & 15;
  const int lk8  = (lane >> 4) << 3;
  const int rr0  = (lane >> 4) << 2;
  const int tt0  = t_lo + tile * (NM * 16);
  const unsigned short* xB = xbb_r + ((size_t)b << 18);

  {
    const int c   = lane;
    const int tap = c >> 5;
    const int cg  = (c & 31) << 3;
    #pragma unroll
    for (int it = 0; it < NM; ++it) {
      int r = it * 16 + w;
      int tt = tt0 + r - tap * dd;
      tt = min(max(tt, 0), 1023);
      gl2lds(xB + ((size_t)tt << 8) + cg, (char*)As + r * 1040);
    }
  }
  const unsigned short* wf0 = Wb + (size_t)(16 * w + l15) * 512 + lk8;
  const unsigned short* wg0 = wf0 + (size_t)256 * 512;
  const unsigned short* wr0 = Wrb + (size_t)(16 * w + l15) * 256 + lk8;
  uint4 nbf = *(const uint4*)(wf0);
  uint4 nbg = *(const uint4*)(wg0);
  uint4 nr0 = *(const uint4*)(wr0);
  __syncthreads();

  f32x4 accf[NM] = {};
  f32x4 accg[NM] = {};
  #pragma unroll 4
  for (int kc = 0; kc < 16; ++kc) {
    uint4 cbf = nbf, cbg = nbg;
    if (kc < 15) {
      nbf = *(const uint4*)(wf0 + (kc + 1) * 32);
      nbg = *(const uint4*)(wg0 + (kc + 1) * 32);
    }
    const int colb = (kc * 32 + lk8) * 2;
    bf16x8 a[NM];
    #pragma unroll
    for (int mf = 0; mf < NM; ++mf)
      a[mf] = *(const bf16x8*)((const char*)As + (mf * 16 + l15) * 1040 + colb);
    bf16x8 vf0 = __builtin_bit_cast(bf16x8, cbf);
    bf16x8 vg0 = __builtin_bit_cast(bf16x8, cbg);
    #pragma unroll
    for (int mf = 0; mf < NM; ++mf) {
      accf[mf] = __builtin_amdgcn_mfma_f32_16x16x32_bf16(a[mf], vf0, accf[mf], 0, 0, 0);
      accg[mf] = __builtin_amdgcn_mfma_f32_16x16x32_bf16(a[mf], vg0, accg[mf], 0, 0, 0);
    }
  }

  const int col = 16 * w + l15;
  float hi_pre[NM][4];
  #pragma unroll
  for (int mf = 0; mf < NM; ++mf)
    #pragma unroll
    for (int j = 0; j < 4; ++j) {
      int row = mf * 16 + rr0 + j;
      hi_pre[mf][j] = bf2f(*(const unsigned short*)((const char*)As + row * 1040 + col * 2));
    }
  unsigned short* xL = xlo + ((size_t)b << 18);
  float lo_pre[NM][4];
  #pragma unroll
  for (int mf = 0; mf < NM; ++mf)
    #pragma unroll
    for (int j = 0; j < 4; ++j) {
      int tt = min(tt0 + mf * 16 + rr0 + j, 1023);
      lo_pre[mf][j] = bf2f(xL[((size_t)tt << 8) + col]);
    }
  __syncthreads();

  unsigned short* Zs = As;
  const float bfv = bF[col];
  const float bgv = bG[col];
  #pragma unroll
  for (int mf = 0; mf < NM; ++mf)
    #pragma unroll
    for (int j = 0; j < 4; ++j) {
      int row = mf * 16 + rr0 + j;
      float pf = accf[mf][j] + bfv;
      float pg = accg[mf][j] + bgv;
      float e2 = __expf(2.f * pf);
      float th = 1.f - 2.f / (e2 + 1.f);
      float sg = 1.f / (1.f + __expf(-pg));
      *(unsigned short*)((char*)Zs + row * 528 + col * 2) = f2bf(th * sg);
    }
  __syncthreads();

  f32x4 acc[NM] = {};
  #pragma unroll 4
  for (int kc = 0; kc < 8; ++kc) {
    uint4 cr0 = nr0;
    if (kc < 7) nr0 = *(const uint4*)(wr0 + (kc + 1) * 32);
    const int colb = (kc * 32 + lk8) * 2;
    bf16x8 a[NM];
    #pragma unroll
    for (int mf = 0; mf < NM; ++mf)
      a[mf] = *(const bf16x8*)((const char*)Zs + (mf * 16 + l15) * 528 + colb);
    bf16x8 v0 = __builtin_bit_cast(bf16x8, cr0);
    #pragma unroll
    for (int mf = 0; mf < NM; ++mf)
      acc[mf] = __builtin_amdgcn_mfma_f32_16x16x32_bf16(a[mf], v0, acc[mf], 0, 0, 0);
  }

  const float brv = bR[col];
  unsigned short* xBb = xbb_w + ((size_t)b << 18);
  #pragma unroll
  for (int mf = 0; mf < NM; ++mf)
    #pragma unroll
    for (int j = 0; j < 4; ++j) {
      int tt = tt0 + mf * 16 + rr0 + j;
      if (tt > 1023) continue;
      size_t off = ((size_t)tt << 8) + col;
      float fx = acc[mf][j] + brv;
      float xn = (hi_pre[mf][j] + lo_pre[mf][j]) + fx;
      unsigned short hn = f2bf(xn);
      xBb[off] = hn;
      xL[off]  = f2bf(xn - bf2f(hn));
      if (tt == 1023) fxs_i[(size_t)b * 256 + col] = fx;
    }
}

// ---------------- fused layer PAIR (i: dilation dd1; i+1: dilation D2<=16) ---------
// Each block: layer i over extended rows [tt0-16, tt0+64) (80 rows, NM1=5),
// x_{i+1} kept in LDS (R2) + regs only (never written to HBM), layer i+1 over
// [tt0, tt0+64) (64 rows). lo ping-pongs (extended read vs owned write).
template<int D2>
__global__ __launch_bounds__(1024, 4) void layer_pair(
    const unsigned short* __restrict__ xhi_r, unsigned short* __restrict__ xhi_w,
    const unsigned short* __restrict__ xlo_r, unsigned short* __restrict__ xlo_w,
    const unsigned short* __restrict__ Wb1, const unsigned short* __restrict__ Wrb1,
    const unsigned short* __restrict__ Wb2, const unsigned short* __restrict__ Wrb2,
    const float* __restrict__ bF1, const float* __restrict__ bG1,
    const float* __restrict__ bR1, const float* __restrict__ bF2,
    const float* __restrict__ bG2, const float* __restrict__ bR2,
    int dd1, int t_lo2, float* __restrict__ fxs1, float* __restrict__ fxs2)
{
  __shared__ __align__(16) unsigned short R1[80 * 520];  // A1 (1040B rows); z1/z2 alias
  __shared__ __align__(16) unsigned short R2[80 * 260];  // x_{i+1} hi (520B rows)
  const int bid  = blockIdx.x;
  const int b    = bid & 15;
  const int tile = bid >> 4;
  const int tid  = threadIdx.x;
  const int w    = tid >> 6;
  const int lane = tid & 63;
  const int l15  = lane & 15;
  const int lk8  = (lane >> 4) << 3;
  const int rr0  = (lane >> 4) << 2;
  const int tt0e = t_lo2 + tile * 64 - 16;    // extended base
  const unsigned short* xH = xhi_r + ((size_t)b << 18);
  const unsigned short* xL = xlo_r + ((size_t)b << 18);

  // ---- stage A1: 80 rows x 512 (two taps of x_i), clamped
  {
    const int c   = lane;
    const int tap = c >> 5;
    const int cg  = (c & 31) << 3;
    #pragma unroll
    for (int it = 0; it < 5; ++it) {
      int r = it * 16 + w;
      int tt = tt0e + r - tap * dd1;
      tt = min(max(tt, 0), 1023);
      gl2lds(xH + ((size_t)tt << 8) + cg, (char*)R1 + r * 1040);
    }
  }
  const unsigned short* wf1 = Wb1 + (size_t)(16 * w + l15) * 512 + lk8;
  const unsigned short* wg1 = wf1 + (size_t)256 * 512;
  const unsigned short* wr1 = Wrb1 + (size_t)(16 * w + l15) * 256 + lk8;
  uint4 nbf = *(const uint4*)(wf1);
  uint4 nbg = *(const uint4*)(wg1);
  uint4 nr  = *(const uint4*)(wr1);
  __syncthreads();   // B1

  // ---- conv1 GEMM: 80 rows x {16 f + 16 g}
  f32x4 accf[5] = {};
  f32x4 accg[5] = {};
  #pragma unroll 4
  for (int kc = 0; kc < 16; ++kc) {
    uint4 cbf = nbf, cbg = nbg;
    if (kc < 15) {
      nbf = *(const uint4*)(wf1 + (kc + 1) * 32);
      nbg = *(const uint4*)(wg1 + (kc + 1) * 32);
    }
    const int colb = (kc * 32 + lk8) * 2;
    bf16x8 a[5];
    #pragma unroll
    for (int mf = 0; mf < 5; ++mf)
      a[mf] = *(const bf16x8*)((const char*)R1 + (mf * 16 + l15) * 1040 + colb);
    bf16x8 vf0 = __builtin_bit_cast(bf16x8, cbf);
    bf16x8 vg0 = __builtin_bit_cast(bf16x8, cbg);
    #pragma unroll
    for (int mf = 0; mf < 5; ++mf) {
      accf[mf] = __builtin_amdgcn_mfma_f32_16x16x32_bf16(a[mf], vf0, accf[mf], 0, 0, 0);
      accg[mf] = __builtin_amdgcn_mfma_f32_16x16x32_bf16(a[mf], vg0, accg[mf], 0, 0, 0);
    }
  }

  // ---- hi_old (x_i) from A1 tap-0; lo_old from global (extended rows)
  const int col = 16 * w + l15;
  float hi_pre[5][4], lo_pre[5][4];
  #pragma unroll
  for (int mf = 0; mf < 5; ++mf)
    #pragma unroll
    for (int j = 0; j < 4; ++j) {
      int row = mf * 16 + rr0 + j;
      hi_pre[mf][j] = bf2f(*(const unsigned short*)((const char*)R1 + row * 1040 + col * 2));
      int tt = min(max(tt0e + row, 0), 1023);
      lo_pre[mf][j] = bf2f(xL[((size_t)tt << 8) + col]);
    }
  __syncthreads();   // B2: A1 reads done

  // ---- gate1 -> z1 in R1 (528B rows)
  {
    const float bfv = bF1[col], bgv = bG1[col];
    #pragma unroll
    for (int mf = 0; mf < 5; ++mf)
      #pragma unroll
      for (int j = 0; j < 4; ++j) {
        int row = mf * 16 + rr0 + j;
        float pf = accf[mf][j] + bfv;
        float pg = accg[mf][j] + bgv;
        float e2 = __expf(2.f * pf);
        float th = 1.f - 2.f / (e2 + 1.f);
        float sg = 1.f / (1.f + __expf(-pg));
        *(unsigned short*)((char*)R1 + row * 528 + col * 2) = f2bf(th * sg);
      }
  }
  __syncthreads();   // B3

  // ---- res1 GEMM K=256 -> fx1; xn1 = hi+lo+fx1; x1 hi -> R2; fxs1 snapshot
  float xn1[5][4];
  {
    f32x4 acc1[5] = {};
    #pragma unroll 4
    for (int kc = 0; kc < 8; ++kc) {
      uint4 cr = nr;
      if (kc < 7) nr = *(const uint4*)(wr1 + (kc + 1) * 32);
      const int colb = (kc * 32 + lk8) * 2;
      bf16x8 a[5];
      #pragma unroll
      for (int mf = 0; mf < 5; ++mf)
        a[mf] = *(const bf16x8*)((const char*)R1 + (mf * 16 + l15) * 528 + colb);
      bf16x8 v0 = __builtin_bit_cast(bf16x8, cr);
      #pragma unroll
      for (int mf = 0; mf < 5; ++mf)
        acc1[mf] = __builtin_amdgcn_mfma_f32_16x16x32_bf16(a[mf], v0, acc1[mf], 0, 0, 0);
    }
    const float br1 = bR1[col];
    #pragma unroll
    for (int mf = 0; mf < 5; ++mf)
      #pragma unroll
      for (int j = 0; j < 4; ++j) {
        int row = mf * 16 + rr0 + j;
        float fx = acc1[mf][j] + br1;
        float xn = (hi_pre[mf][j] + lo_pre[mf][j]) + fx;
        xn1[mf][j] = xn;
        *(unsigned short*)((char*)R2 + row * 520 + col * 2) = f2bf(xn);
        if (tt0e + row == 1023) fxs1[(size_t)b * 256 + col] = fx;
      }
  }
  const unsigned short* wf2 = Wb2 + (size_t)(16 * w + l15) * 512 + lk8;
  const unsigned short* wg2 = wf2 + (size_t)256 * 512;
  const unsigned short* wr2 = Wrb2 + (size_t)(16 * w + l15) * 256 + lk8;
  nbf = *(const uint4*)(wf2);
  nbg = *(const uint4*)(wg2);
  __syncthreads();   // B4: R2 (x1 hi) visible

  // ---- conv2 GEMM: 64 rows (r' in [16,80)), taps from R2 (tap1 row -= D2)
  f32x4 acc2f[4] = {};
  f32x4 acc2g[4] = {};
  #pragma unroll 4
  for (int kc = 0; kc < 16; ++kc) {
    uint4 cbf = nbf, cbg = nbg;
    if (kc < 15) {
      nbf = *(const uint4*)(wf2 + (kc + 1) * 32);
      nbg = *(const uint4*)(wg2 + (kc + 1) * 32);
    }
    const int tapofs = (kc >= 8) ? D2 : 0;
    const int colb = ((kc & 7) * 32 + lk8) * 2;
    bf16x8 a[4];
    #pragma unroll
    for (int mf = 0; mf < 4; ++mf)
      a[mf] = *(const bf16x8*)((const char*)R2 + (16 + mf * 16 + l15 - tapofs) * 520 + colb);
    bf16x8 vf0 = __builtin_bit_cast(bf16x8, cbf);
    bf16x8 vg0 = __builtin_bit_cast(bf16x8, cbg);
    #pragma unroll
    for (int mf = 0; mf < 4; ++mf) {
      acc2f[mf] = __builtin_amdgcn_mfma_f32_16x16x32_bf16(a[mf], vf0, acc2f[mf], 0, 0, 0);
      acc2g[mf] = __builtin_amdgcn_mfma_f32_16x16x32_bf16(a[mf], vg0, acc2g[mf], 0, 0, 0);
    }
  }
  nr = *(const uint4*)(wr2);

  // ---- gate2 -> z2 into R1 rows 0..63 (disjoint from conv2's R2 reads)
  {
    const float bfv = bF2[col], bgv = bG2[col];
    #pragma unroll
    for (int mf = 0; mf < 4; ++mf)
      #pragma unroll
      for (int j = 0; j < 4; ++j) {
        int row = mf * 16 + rr0 + j;
        float pf = acc2f[mf][j] + bfv;
        float pg = acc2g[mf][j] + bgv;
        float e2 = __expf(2.f * pf);
        float th = 1.f - 2.f / (e2 + 1.f);
        float sg = 1.f / (1.f + __expf(-pg));
        *(unsigned short*)((char*)R1 + row * 528 + col * 2) = f2bf(th * sg);
      }
  }
  __syncthreads();   // B5

  // ---- res2 GEMM K=256 -> fx2; xn2 = xn1(shifted) + fx2; write hi/lo; fxs2
  {
    f32x4 acc2[4] = {};
    #pragma unroll 4
    for (int kc = 0; kc < 8; ++kc) {
      uint4 cr = nr;
      if (kc < 7) nr = *(const uint4*)(wr2 + (kc + 1) * 32);
      const int colb = (kc * 32 + lk8) * 2;
      bf16x8 a[4];
      #pragma unroll
      for (int mf = 0; mf < 4; ++mf)
        a[mf] = *(const bf16x8*)((const char*)R1 + (mf * 16 + l15) * 528 + colb);
      bf16x8 v0 = __builtin_bit_cast(bf16x8, cr);
      #pragma unroll
      for (int mf = 0; mf < 4; ++mf)
        acc2[mf] = __builtin_amdgcn_mfma_f32_16x16x32_bf16(a[mf], v0, acc2[mf], 0, 0, 0);
    }
    const float br2 = bR2[col];
    unsigned short* oH = xhi_w + ((size_t)b << 18);
    unsigned short* oL = xlo_w + ((size_t)b << 18);
    #pragma unroll
    for (int mf = 0; mf < 4; ++mf)
      #pragma unroll
      for (int j = 0; j < 4; ++j) {
        int row = 16 + mf * 16 + rr0 + j;
        int tt = tt0e + row;
        if (tt > 1023) continue;
        size_t off = ((size_t)tt << 8) + col;
        float fx2 = acc2[mf][j] + br2;
        float xn2 = xn1[mf + 1][j] + fx2;
        unsigned short hn = f2bf(xn2);
        oH[off] = hn;
        oL[off] = f2bf(xn2 - bf2f(hn));
        if (tt == 1023) fxs2[(size_t)b * 256 + col] = fx2;
      }
  }
}

// ---------------- head ----------------
__global__ __launch_bounds__(128) void skip_partial(
    const float* __restrict__ fxs, const float* __restrict__ wskT,
    const float* __restrict__ b_skip, float* __restrict__ part)
{
  int i = blockIdx.x, b = blockIdx.y, s = threadIdx.x;
  __shared__ float fxsh[256];
  fxsh[s]       = fxs[((size_t)i * 16 + b) * 256 + s];
  fxsh[s + 128] = fxs[((size_t)i * 16 + b) * 256 + s + 128];
  __syncthreads();
  float a = b_skip[i * 128 + s];
  const float* wp = wskT + (size_t)i * 256 * 128 + s;
  #pragma unroll 4
  for (int c = 0; c < 256; c++)
    a = fmaf(wp[c * 128], fxsh[c], a);
  part[((size_t)i * 16 + b) * 128 + s] = a;
}

__global__ __launch_bounds__(128) void head2(
    const float* __restrict__ part, const float* __restrict__ w_o1,
    const float* __restrict__ b_o1, const float* __restrict__ w_o2,
    const float* __restrict__ b_o2, const float* __restrict__ w_lin,
    const float* __restrict__ b_lin, const float* __restrict__ Xex,
    float* __restrict__ out)
{
  int b = blockIdx.x, tid = threadIdx.x;
  __shared__ float sk[128];
  __shared__ float h1[64];
  __shared__ float hc[80];
  float a = 0.f;
  for (int i = 0; i < 32; i++) a += part[((size_t)i * 16 + b) * 128 + tid];
  sk[tid] = fmaxf(a, 0.f);
  __syncthreads();
  if (tid < 64) {
    float a1 = b_o1[tid];
    for (int s = 0; s < 128; s++) a1 = fmaf(w_o1[tid * 128 + s], sk[s], a1);
    h1[tid] = fmaxf(a1, 0.f);
  }
  __syncthreads();
  if (tid < 64) {
    float a2 = b_o2[tid];
    for (int j = 0; j < 64; j++) a2 = fmaf(w_o2[tid * 64 + j], h1[j], a2);
    hc[tid] = fmaxf(a2, 0.f);
  }
  if (tid >= 64 && tid < 80) hc[tid] = fmaxf(Xex[b * 16 + (tid - 64)], 0.f);
  __syncthreads();
  if (tid < 24) {
    float a3 = b_lin[tid];
    for (int j = 0; j < 80; j++) a3 = fmaf(w_lin[tid * 80 + j], hc[j], a3);
    out[b * 24 + tid] = a3;
  }
}

extern "C" void kernel_launch(void* const* d_in, const int* in_sizes, int n_in,
                              void* d_out, int out_size, void* d_ws, size_t ws_size,
                              hipStream_t stream)
{
  (void)in_sizes; (void)n_in; (void)out_size; (void)ws_size;
  const float* X     = (const float*)d_in[0];
  const float* Xex   = (const float*)d_in[1];
  const float* w_in  = (const float*)d_in[2];
  const float* b_in  = (const float*)d_in[3];
  const float* w_f   = (const float*)d_in[4];
  const float* b_f   = (const float*)d_in[5];
  const float* w_g   = (const float*)d_in[6];
  const float* b_g   = (const float*)d_in[7];
  const float* w_r   = (const float*)d_in[8];
  const float* b_r   = (const float*)d_in[9];
  const float* w_s   = (const float*)d_in[10];
  const float* b_s   = (const float*)d_in[11];
  const float* w_o1  = (const float*)d_in[12];
  const float* b_o1  = (const float*)d_in[13];
  const float* w_o2  = (const float*)d_in[14];
  const float* b_o2  = (const float*)d_in[15];
  const float* w_lin = (const float*)d_in[16];
  const float* b_lin = (const float*)d_in[17];

  float* ws   = (float*)d_ws;
  float* wskT = ws;                        // 1,048,576 f
  float* fxs  = wskT + 1048576;            // 131,072 f
  float* part = fxs  + 131072;             // 65,536 f
  float* w2   = part + 65536;              // 16,384 f
  unsigned short* Wb   = (unsigned short*)(w2 + 16384);    // 8,388,608 us
  unsigned short* Wrb  = Wb   + 8388608;   // 2,097,152 us
  unsigned short* hiA  = Wrb  + 2097152;   // 4,194,304 us
  unsigned short* hiB  = hiA  + 4194304;   // 4,194,304 us
  unsigned short* loA  = hiB  + 4194304;   // 4,194,304 us
  unsigned short* loB  = loA  + 4194304;   // 4,194,304 us

  prep<<<22592, 256, 0, stream>>>(w_f, w_g, w_r, w_s, w_in, Wb, Wrb, wskT, w2);
  in_conv<<<1024, 256, 0, stream>>>(X, w2, b_in, hiA, loA);

  // suffix-window sizes: w[i] = w[i+1] + 2^(i%8), w[32] = 1
  static const int wI[33] = {1021,1020,1018,1014,1006,990,958,894,
                             766,765,763,759,751,735,703,639,
                             511,510,508,504,496,480,448,384,
                             256,255,253,249,241,225,193,129,1};
  unsigned short* hi_c = hiA; unsigned short* hi_n = hiB;
  unsigned short* lo_c = loA; unsigned short* lo_n = loB;
  int i = 0;
  while (i < 32) {
    const int m = i & 7;
    if (m == 0 || m == 2) {
      // fuse (i, i+1): d2 = 2 (m==0) or 8 (m==2), extension 16
      const int d2   = 1 << ((i + 1) & 7);
      const int dd1  = 1 << m;
      const int W2   = wI[i + 2];
      const int t_lo2 = TBUF - W2;
      const int tiles = (W2 + 63) / 64;
      if (d2 == 2)
        layer_pair<2><<<tiles * 16, 1024, 0, stream>>>(
            hi_c, hi_n, lo_c, lo_n,
            Wb + (size_t)i * 262144, Wrb + (size_t)i * 65536,
            Wb + (size_t)(i + 1) * 262144, Wrb + (size_t)(i + 1) * 65536,
            b_f + i * 256, b_g + i * 256, b_r + i * 256,
            b_f + (i + 1) * 256, b_g + (i + 1) * 256, b_r + (i + 1) * 256,
            dd1, t_lo2, fxs + (size_t)i * 4096, fxs + (size_t)(i + 1) * 4096);
      else
        layer_pair<8><<<tiles * 16, 1024, 0, stream>>>(
            hi_c, hi_n, lo_c, lo_n,
            Wb + (size_t)i * 262144, Wrb + (size_t)i * 65536,
            Wb + (size_t)(i + 1) * 262144, Wrb + (size_t)(i + 1) * 65536,
            b_f + i * 256, b_g + i * 256, b_r + i * 256,
            b_f + (i + 1) * 256, b_g + (i + 1) * 256, b_r + (i + 1) * 256,
            dd1, t_lo2, fxs + (size_t)i * 4096, fxs + (size_t)(i + 1) * 4096);
      { unsigned short* t = hi_c; hi_c = hi_n; hi_n = t; }
      { unsigned short* t = lo_c; lo_c = lo_n; lo_n = t; }
      i += 2;
    } else {
      const int dd    = 1 << m;
      const int Wout  = wI[i + 1];
      const int t_lo  = TBUF - Wout;
      const int NM    = (Wout + 255) >> 8;
      const int tiles = (Wout + NM * 16 - 1) / (NM * 16);
      const unsigned short* WbL  = Wb  + (size_t)i * 262144;
      const unsigned short* WrbL = Wrb + (size_t)i * 65536;
      const float* bFi = b_f + i * 256;
      const float* bGi = b_g + i * 256;
      const float* bRi = b_r + i * 256;
      float* fxi = fxs + (size_t)i * 4096;
      switch (NM) {
        case 4: layer_fused<4><<<tiles * 16, 1024, 0, stream>>>(
                    hi_c, hi_n, lo_c, WbL, WrbL, bFi, bGi, bRi, dd, t_lo, fxi); break;
        case 3: layer_fused<3><<<tiles * 16, 1024, 0, stream>>>(
                    hi_c, hi_n, lo_c, WbL, WrbL, bFi, bGi, bRi, dd, t_lo, fxi); break;
        case 2: layer_fused<2><<<tiles * 16, 1024, 0, stream>>>(
                    hi_c, hi_n, lo_c, WbL, WrbL, bFi, bGi, bRi, dd, t_lo, fxi); break;
        default: layer_fused<1><<<tiles * 16, 1024, 0, stream>>>(
                    hi_c, hi_n, lo_c, WbL, WrbL, bFi, bGi, bRi, dd, t_lo, fxi); break;
      }
      { unsigned short* t = hi_c; hi_c = hi_n; hi_n = t; }
      i += 1;
    }
  }
  skip_partial<<<dim3(32, 16), 128, 0, stream>>>(fxs, wskT, b_s, part);
  head2<<<16, 128, 0, stream>>>(part, w_o1, b_o1, w_o2, b_o2, w_lin, b_lin, Xex, (float*)d_out);
}

// Round 18
// 885.121 us; speedup vs baseline: 1.0641x; 1.0641x over previous
//
#include <hip/hip_runtime.h>
#include <cmath>

#define TBUF 1024
#define RCH  256

typedef __bf16 bf16x8 __attribute__((ext_vector_type(8)));
typedef float  f32x4  __attribute__((ext_vector_type(4)));

__device__ inline unsigned short f2bf(float f) {
  unsigned u = __builtin_bit_cast(unsigned, f);
  u += 0x7FFFu + ((u >> 16) & 1u);
  return (unsigned short)(u >> 16);
}
__device__ inline float bf2f(unsigned short h) {
  unsigned u = ((unsigned)h) << 16;
  return __builtin_bit_cast(float, u);
}

// ---------------- merged weight transforms (one dispatch) ----------------
__global__ __launch_bounds__(256) void prep(
    const float* __restrict__ wf, const float* __restrict__ wg,
    const float* __restrict__ wr, const float* __restrict__ wsk,
    const float* __restrict__ w_in,
    unsigned short* __restrict__ Wb, unsigned short* __restrict__ Wrb,
    float* __restrict__ wskT, float* __restrict__ w2)
{
  const int bid = blockIdx.x;
  const int tid = threadIdx.x;
  if (bid < 16384) {
    int idx = bid * 256 + tid;
    int c  = idx & 255;
    int op = (idx >> 8) & 511;
    int i  = idx >> 17;
    int o  = op & 255;
    const float* src = (op < 256) ? wf : wg;
    const float2 v = *(const float2*)&src[(((size_t)i * 256 + o) * 256 + c) << 1];
    unsigned short* dst = Wb + ((size_t)i * 512 + op) * 512;
    dst[c]       = f2bf(v.y);   // current tap (k=1)
    dst[256 + c] = f2bf(v.x);   // previous tap (k=0)
  } else if (bid < 18432) {
    int idx = (bid - 16384) * 256 + tid;
    float4 v = ((const float4*)wr)[idx];
    uint2 o;
    o.x = (unsigned)f2bf(v.x) | ((unsigned)f2bf(v.y) << 16);
    o.y = (unsigned)f2bf(v.z) | ((unsigned)f2bf(v.w) << 16);
    ((uint2*)Wrb)[idx] = o;
  } else if (bid < 22528) {
    int idx = (bid - 18432) * 256 + tid;
    int s = idx & 127;
    int c = (idx >> 7) & 255;
    int i = idx >> 15;
    wskT[idx] = wsk[(i * 128 + s) * 256 + c];
  } else {
    int idx = (bid - 22528) * 256 + tid;
    int r = idx & 255;
    int fk = idx >> 8;
    int f = fk & 31, k = fk >> 5;
    w2[idx] = w_in[r * 64 + f * 2 + k];
  }
}

// ---------------- input conv (F=32 -> R=256, K=2, d=1) ----------------
__global__ __launch_bounds__(256) void in_conv(
    const float* __restrict__ X, const float* __restrict__ w2,
    const float* __restrict__ b_in, unsigned short* __restrict__ xbb,
    unsigned short* __restrict__ xlo)
{
  const int bid   = blockIdx.x;
  const int b     = bid & 15;
  const int chunk = bid >> 4;
  const int r     = threadIdx.x;
  __shared__ float Xs[17][32];
  const int tt0 = chunk << 4;
  const int t0  = tt0 + 1024;
  for (int idx = r; idx < 17 * 32; idx += 256) {
    int row = idx >> 5, f = idx & 31;
    Xs[row][f] = X[((size_t)b * 2048 + (t0 - 1 + row)) * 32 + f];
  }
  __syncthreads();
  float w0[32], w1[32];
  #pragma unroll
  for (int f = 0; f < 32; ++f) {
    w0[f] = w2[f * 256 + r];
    w1[f] = w2[(32 + f) * 256 + r];
  }
  const float bias = b_in[r];
  float4 prev[8], cur[8];
  #pragma unroll
  for (int q = 0; q < 8; ++q) prev[q] = *(const float4*)&Xs[0][q * 4];
  #pragma unroll
  for (int j = 0; j < 16; ++j) {
    #pragma unroll
    for (int q = 0; q < 8; ++q) cur[q] = *(const float4*)&Xs[j + 1][q * 4];
    float a = bias;
    #pragma unroll
    for (int q = 0; q < 8; ++q) {
      a = fmaf(w0[q*4+0], prev[q].x, a); a = fmaf(w1[q*4+0], cur[q].x, a);
      a = fmaf(w0[q*4+1], prev[q].y, a); a = fmaf(w1[q*4+1], cur[q].y, a);
      a = fmaf(w0[q*4+2], prev[q].z, a); a = fmaf(w1[q*4+2], cur[q].z, a);
      a = fmaf(w0[q*4+3], prev[q].w, a); a = fmaf(w1[q*4+3], cur[q].w, a);
    }
    int tt = tt0 + j;
    size_t off = ((size_t)b * TBUF + tt) * RCH + r;
    if (tt < 3) { xbb[off] = 0; xlo[off] = 0; }
    else {
      unsigned short hn = f2bf(a);
      xbb[off] = hn;
      xlo[off] = f2bf(a - bf2f(hn));
    }
    #pragma unroll
    for (int q = 0; q < 8; ++q) prev[q] = cur[q];
  }
}

// ---------------- fused layer, adaptive M = NM*16 rows per block -------------
// 1024 thr = 16 waves. Wave w owns 16 f-cols + 16 g-cols (conv), 16 cols (res).
// Split-precision residual (hi/lo bf16); hi_old re-read from A-tile LDS.
// NM = ceil(W/256) -> smallest per-block work with grid <= 256.
// 1-deep weight ping-pong; kc=0 weights + lo_pre issued pre-barrier so their
// latency overlaps the gload_lds drain / gate epilogue. Only small scalars are
// held across barriers (the 64-VGPR array hoist spills: r4/r8/r12/r17).
template<int NM>
__global__ __launch_bounds__(1024, 4) void layer_fused(
    const unsigned short* __restrict__ xbb_r, unsigned short* __restrict__ xbb_w,
    unsigned short* __restrict__ xlo,
    const unsigned short* __restrict__ Wb,   // [512][512] bf16
    const unsigned short* __restrict__ Wrb,  // [256][256] bf16
    const float* __restrict__ bF, const float* __restrict__ bG,
    const float* __restrict__ bR,
    int dd, int t_lo, float* __restrict__ fxs_i)
{
  __shared__ __align__(16) unsigned short As[NM * 16 * 520];  // z aliases
  const int bid  = blockIdx.x;
  const int b    = bid & 15;
  const int tile = bid >> 4;
  const int tid  = threadIdx.x;
  const int w    = tid >> 6;          // 0..15
  const int lane = tid & 63;
  const int l15  = lane & 15;
  const int lk8  = (lane >> 4) << 3;
  const int rr0  = (lane >> 4) << 2;
  const int tt0  = t_lo + tile * (NM * 16);
  const unsigned short* xB = xbb_r + ((size_t)b << 18);

  // ---- stage A tile via global_load_lds: NM*16 rows x 512 k (NM rows/wave)
  {
    const int c   = lane;
    const int tap = c >> 5;
    const int cg  = (c & 31) << 3;
    #pragma unroll
    for (int it = 0; it < NM; ++it) {
      int r = it * 16 + w;
      int tt = tt0 + r - tap * dd;
      tt = min(max(tt, 0), 1023);
      __builtin_amdgcn_global_load_lds(
          (const __attribute__((address_space(1))) unsigned int*)
              (xB + ((size_t)tt << 8) + cg),
          (__attribute__((address_space(3))) unsigned int*)
              ((char*)As + r * 1040),
          16, 0, 0);
    }
  }

  // ---- preload first conv/res weight chunks BEFORE the barrier:
  //      their L2 latency overlaps the gload_lds drain.
  const unsigned short* wf0 = Wb + (size_t)(16 * w + l15) * 512 + lk8;
  const unsigned short* wg0 = wf0 + (size_t)256 * 512;
  const unsigned short* wr0 = Wrb + (size_t)(16 * w + l15) * 256 + lk8;
  uint4 nbf = *(const uint4*)(wf0);
  uint4 nbg = *(const uint4*)(wg0);
  uint4 nr0 = *(const uint4*)(wr0);
  __syncthreads();

  // ---- conv GEMM: per wave (NM*16)(M) x {16 f + 16 g}, 1-deep B ping-pong
  f32x4 accf[NM] = {};
  f32x4 accg[NM] = {};
  #pragma unroll 4
  for (int kc = 0; kc < 16; ++kc) {
    uint4 cbf = nbf, cbg = nbg;
    if (kc < 15) {
      nbf = *(const uint4*)(wf0 + (kc + 1) * 32);
      nbg = *(const uint4*)(wg0 + (kc + 1) * 32);
    }
    const int colb = (kc * 32 + lk8) * 2;
    bf16x8 a[NM];
    #pragma unroll
    for (int mf = 0; mf < NM; ++mf)
      a[mf] = *(const bf16x8*)((const char*)As + (mf * 16 + l15) * 1040 + colb);
    bf16x8 vf0 = __builtin_bit_cast(bf16x8, cbf);
    bf16x8 vg0 = __builtin_bit_cast(bf16x8, cbg);
    #pragma unroll
    for (int mf = 0; mf < NM; ++mf) {
      accf[mf] = __builtin_amdgcn_mfma_f32_16x16x32_bf16(a[mf], vf0, accf[mf], 0, 0, 0);
      accg[mf] = __builtin_amdgcn_mfma_f32_16x16x32_bf16(a[mf], vg0, accg[mf], 0, 0, 0);
    }
  }

  // ---- re-read hi_old from the A-tile LDS (tap-0 region) BEFORE z overwrite
  const int col = 16 * w + l15;
  float hi_pre[NM][4];
  #pragma unroll
  for (int mf = 0; mf < NM; ++mf)
    #pragma unroll
    for (int j = 0; j < 4; ++j) {
      int row = mf * 16 + rr0 + j;
      hi_pre[mf][j] = bf2f(*(const unsigned short*)((const char*)As + row * 1040 + col * 2));
    }

  // ---- lo_old loads issued HERE (independent of z; latency hides under
  //      gate epilogue + barrier + res GEMM)
  unsigned short* xL = xlo + ((size_t)b << 18);
  float lo_pre[NM][4];
  #pragma unroll
  for (int mf = 0; mf < NM; ++mf)
    #pragma unroll
    for (int j = 0; j < 4; ++j) {
      int tt = min(tt0 + mf * 16 + rr0 + j, 1023);
      lo_pre[mf][j] = bf2f(xL[((size_t)tt << 8) + col]);
    }
  __syncthreads();   // all As reads done -> safe to overwrite with z

  // ---- gate epilogue: z = tanh(f+bf) * sigmoid(g+bg) -> LDS (aliased)
  unsigned short* Zs = As;
  const float bfv = bF[col];
  const float bgv = bG[col];
  #pragma unroll
  for (int mf = 0; mf < NM; ++mf)
    #pragma unroll
    for (int j = 0; j < 4; ++j) {
      int row = mf * 16 + rr0 + j;
      float pf = accf[mf][j] + bfv;
      float pg = accg[mf][j] + bgv;
      float e2 = __expf(2.f * pf);
      float th = 1.f - 2.f / (e2 + 1.f);
      float sg = 1.f / (1.f + __expf(-pg));
      *(unsigned short*)((char*)Zs + row * 528 + col * 2) = f2bf(th * sg);
    }
  __syncthreads();

  // ---- res GEMM: per wave (NM*16)(M) x 16(N), K=256, 1-deep B ping-pong
  f32x4 acc[NM] = {};
  #pragma unroll 4
  for (int kc = 0; kc < 8; ++kc) {
    uint4 cr0 = nr0;
    if (kc < 7) nr0 = *(const uint4*)(wr0 + (kc + 1) * 32);
    const int colb = (kc * 32 + lk8) * 2;
    bf16x8 a[NM];
    #pragma unroll
    for (int mf = 0; mf < NM; ++mf)
      a[mf] = *(const bf16x8*)((const char*)Zs + (mf * 16 + l15) * 528 + colb);
    bf16x8 v0 = __builtin_bit_cast(bf16x8, cr0);
    #pragma unroll
    for (int mf = 0; mf < NM; ++mf)
      acc[mf] = __builtin_amdgcn_mfma_f32_16x16x32_bf16(a[mf], v0, acc[mf], 0, 0, 0);
  }

  // ---- residual epilogue: xn = (hi+lo) + fx; re-split to hi'/lo'; fx snapshot
  const float brv = bR[col];
  unsigned short* xBb = xbb_w + ((size_t)b << 18);
  #pragma unroll
  for (int mf = 0; mf < NM; ++mf)
    #pragma unroll
    for (int j = 0; j < 4; ++j) {
      int tt = tt0 + mf * 16 + rr0 + j;
      if (tt > 1023) continue;
      size_t off = ((size_t)tt << 8) + col;
      float fx = acc[mf][j] + brv;
      float xn = (hi_pre[mf][j] + lo_pre[mf][j]) + fx;
      unsigned short hn = f2bf(xn);
      xBb[off] = hn;
      xL[off]  = f2bf(xn - bf2f(hn));
      if (tt == 1023) fxs_i[(size_t)b * 256 + col] = fx;
    }
}

// ---------------- head ----------------
__global__ __launch_bounds__(128) void skip_partial(
    const float* __restrict__ fxs, const float* __restrict__ wskT,
    const float* __restrict__ b_skip, float* __restrict__ part)
{
  int i = blockIdx.x, b = blockIdx.y, s = threadIdx.x;
  __shared__ float fxsh[256];
  fxsh[s]       = fxs[((size_t)i * 16 + b) * 256 + s];
  fxsh[s + 128] = fxs[((size_t)i * 16 + b) * 256 + s + 128];
  __syncthreads();
  float a = b_skip[i * 128 + s];
  const float* wp = wskT + (size_t)i * 256 * 128 + s;
  #pragma unroll 4
  for (int c = 0; c < 256; c++)
    a = fmaf(wp[c * 128], fxsh[c], a);
  part[((size_t)i * 16 + b) * 128 + s] = a;
}

__global__ __launch_bounds__(128) void head2(
    const float* __restrict__ part, const float* __restrict__ w_o1,
    const float* __restrict__ b_o1, const float* __restrict__ w_o2,
    const float* __restrict__ b_o2, const float* __restrict__ w_lin,
    const float* __restrict__ b_lin, const float* __restrict__ Xex,
    float* __restrict__ out)
{
  int b = blockIdx.x, tid = threadIdx.x;
  __shared__ float sk[128];
  __shared__ float h1[64];
  __shared__ float hc[80];
  float a = 0.f;
  for (int i = 0; i < 32; i++) a += part[((size_t)i * 16 + b) * 128 + tid];
  sk[tid] = fmaxf(a, 0.f);
  __syncthreads();
  if (tid < 64) {
    float a1 = b_o1[tid];
    for (int s = 0; s < 128; s++) a1 = fmaf(w_o1[tid * 128 + s], sk[s], a1);
    h1[tid] = fmaxf(a1, 0.f);
  }
  __syncthreads();
  if (tid < 64) {
    float a2 = b_o2[tid];
    for (int j = 0; j < 64; j++) a2 = fmaf(w_o2[tid * 64 + j], h1[j], a2);
    hc[tid] = fmaxf(a2, 0.f);
  }
  if (tid >= 64 && tid < 80) hc[tid] = fmaxf(Xex[b * 16 + (tid - 64)], 0.f);
  __syncthreads();
  if (tid < 24) {
    float a3 = b_lin[tid];
    for (int j = 0; j < 80; j++) a3 = fmaf(w_lin[tid * 80 + j], hc[j], a3);
    out[b * 24 + tid] = a3;
  }
}

extern "C" void kernel_launch(void* const* d_in, const int* in_sizes, int n_in,
                              void* d_out, int out_size, void* d_ws, size_t ws_size,
                              hipStream_t stream)
{
  (void)in_sizes; (void)n_in; (void)out_size; (void)ws_size;
  const float* X     = (const float*)d_in[0];
  const float* Xex   = (const float*)d_in[1];
  const float* w_in  = (const float*)d_in[2];
  const float* b_in  = (const float*)d_in[3];
  const float* w_f   = (const float*)d_in[4];
  const float* b_f   = (const float*)d_in[5];
  const float* w_g   = (const float*)d_in[6];
  const float* b_g   = (const float*)d_in[7];
  const float* w_r   = (const float*)d_in[8];
  const float* b_r   = (const float*)d_in[9];
  const float* w_s   = (const float*)d_in[10];
  const float* b_s   = (const float*)d_in[11];
  const float* w_o1  = (const float*)d_in[12];
  const float* b_o1  = (const float*)d_in[13];
  const float* w_o2  = (const float*)d_in[14];
  const float* b_o2  = (const float*)d_in[15];
  const float* w_lin = (const float*)d_in[16];
  const float* b_lin = (const float*)d_in[17];

  float* ws   = (float*)d_ws;
  float* wskT = ws;                        // 1,048,576 f
  float* fxs  = wskT + 1048576;            // 131,072 f
  float* part = fxs  + 131072;             // 65,536 f
  float* w2   = part + 65536;              // 16,384 f
  unsigned short* Wb   = (unsigned short*)(w2 + 16384);    // 8,388,608 us
  unsigned short* Wrb  = Wb   + 8388608;   // 2,097,152 us
  unsigned short* xbbA = Wrb  + 2097152;   // 4,194,304 us
  unsigned short* xbbB = xbbA + 4194304;   // 4,194,304 us
  unsigned short* xlo  = xbbB + 4194304;   // 4,194,304 us

  prep<<<22592, 256, 0, stream>>>(w_f, w_g, w_r, w_s, w_in, Wb, Wrb, wskT, w2);
  in_conv<<<1024, 256, 0, stream>>>(X, w2, b_in, xbbA, xlo);

  // suffix-window sizes: w[i] = w[i+1] + 2^(i%8), w[32] = 1
  static const int wI[33] = {1021,1020,1018,1014,1006,990,958,894,
                             766,765,763,759,751,735,703,639,
                             511,510,508,504,496,480,448,384,
                             256,255,253,249,241,225,193,129,1};
  for (int i = 0; i < 32; i++) {
    int dd    = 1 << (i & 7);
    int Wout  = wI[i + 1];
    int t_lo  = TBUF - Wout;
    unsigned short* xin  = (i & 1) ? xbbB : xbbA;
    unsigned short* xout = (i & 1) ? xbbA : xbbB;
    const unsigned short* WbL  = Wb  + (size_t)i * 262144;
    const unsigned short* WrbL = Wrb + (size_t)i * 65536;
    const float* bFi = b_f + i * 256;
    const float* bGi = b_g + i * 256;
    const float* bRi = b_r + i * 256;
    float* fxi = fxs + (size_t)i * 4096;
    // NM = ceil(W/256): smallest per-block work with grid <= 256 blocks.
    int NM = (Wout + 255) >> 8;
    int tiles = (Wout + NM * 16 - 1) / (NM * 16);
    switch (NM) {
      case 4:
        layer_fused<4><<<tiles * 16, 1024, 0, stream>>>(
            xin, xout, xlo, WbL, WrbL, bFi, bGi, bRi, dd, t_lo, fxi);
        break;
      case 3:
        layer_fused<3><<<tiles * 16, 1024, 0, stream>>>(
            xin, xout, xlo, WbL, WrbL, bFi, bGi, bRi, dd, t_lo, fxi);
        break;
      case 2:
        layer_fused<2><<<tiles * 16, 1024, 0, stream>>>(
            xin, xout, xlo, WbL, WrbL, bFi, bGi, bRi, dd, t_lo, fxi);
        break;
      default:
        layer_fused<1><<<tiles * 16, 1024, 0, stream>>>(
            xin, xout, xlo, WbL, WrbL, bFi, bGi, bRi, dd, t_lo, fxi);
        break;
    }
  }
  skip_partial<<<dim3(32, 16), 128, 0, stream>>>(fxs, wskT, b_s, part);
  head2<<<16, 128, 0, stream>>>(part, w_o1, b_o1, w_o2, b_o2, w_lin, b_lin, Xex, (float*)d_out);
}

// Round 19
// 862.763 us; speedup vs baseline: 1.0917x; 1.0259x over previous
//
#include <hip/hip_runtime.h>
#include <cmath>

#define TBUF 1024
#define RCH  256

typedef __bf16 bf16x8 __attribute__((ext_vector_type(8)));
typedef float  f32x4  __attribute__((ext_vector_type(4)));

__device__ inline unsigned short f2bf(float f) {
  unsigned u = __builtin_bit_cast(unsigned, f);
  u += 0x7FFFu + ((u >> 16) & 1u);
  return (unsigned short)(u >> 16);
}
__device__ inline float bf2f(unsigned short h) {
  unsigned u = ((unsigned)h) << 16;
  return __builtin_bit_cast(float, u);
}

// ---------------- merged weight transforms (one dispatch) ----------------
__global__ __launch_bounds__(256) void prep(
    const float* __restrict__ wf, const float* __restrict__ wg,
    const float* __restrict__ wr, const float* __restrict__ wsk,
    const float* __restrict__ w_in,
    unsigned short* __restrict__ Wb, unsigned short* __restrict__ Wrb,
    float* __restrict__ wskT, float* __restrict__ w2)
{
  const int bid = blockIdx.x;
  const int tid = threadIdx.x;
  if (bid < 16384) {
    int idx = bid * 256 + tid;
    int c  = idx & 255;
    int op = (idx >> 8) & 511;
    int i  = idx >> 17;
    int o  = op & 255;
    const float* src = (op < 256) ? wf : wg;
    const float2 v = *(const float2*)&src[(((size_t)i * 256 + o) * 256 + c) << 1];
    unsigned short* dst = Wb + ((size_t)i * 512 + op) * 512;
    dst[c]       = f2bf(v.y);   // current tap (k=1)
    dst[256 + c] = f2bf(v.x);   // previous tap (k=0)
  } else if (bid < 18432) {
    int idx = (bid - 16384) * 256 + tid;
    float4 v = ((const float4*)wr)[idx];
    uint2 o;
    o.x = (unsigned)f2bf(v.x) | ((unsigned)f2bf(v.y) << 16);
    o.y = (unsigned)f2bf(v.z) | ((unsigned)f2bf(v.w) << 16);
    ((uint2*)Wrb)[idx] = o;
  } else if (bid < 22528) {
    int idx = (bid - 18432) * 256 + tid;
    int s = idx & 127;
    int c = (idx >> 7) & 255;
    int i = idx >> 15;
    wskT[idx] = wsk[(i * 128 + s) * 256 + c];
  } else {
    int idx = (bid - 22528) * 256 + tid;
    int r = idx & 255;
    int fk = idx >> 8;
    int f = fk & 31, k = fk >> 5;
    w2[idx] = w_in[r * 64 + f * 2 + k];
  }
}

// ---------------- input conv (F=32 -> R=256, K=2, d=1) ----------------
__global__ __launch_bounds__(256) void in_conv(
    const float* __restrict__ X, const float* __restrict__ w2,
    const float* __restrict__ b_in, unsigned short* __restrict__ xbb,
    unsigned short* __restrict__ xlo)
{
  const int bid   = blockIdx.x;
  const int b     = bid & 15;
  const int chunk = bid >> 4;
  const int r     = threadIdx.x;
  __shared__ float Xs[17][32];
  const int tt0 = chunk << 4;
  const int t0  = tt0 + 1024;
  for (int idx = r; idx < 17 * 32; idx += 256) {
    int row = idx >> 5, f = idx & 31;
    Xs[row][f] = X[((size_t)b * 2048 + (t0 - 1 + row)) * 32 + f];
  }
  __syncthreads();
  float w0[32], w1[32];
  #pragma unroll
  for (int f = 0; f < 32; ++f) {
    w0[f] = w2[f * 256 + r];
    w1[f] = w2[(32 + f) * 256 + r];
  }
  const float bias = b_in[r];
  float4 prev[8], cur[8];
  #pragma unroll
  for (int q = 0; q < 8; ++q) prev[q] = *(const float4*)&Xs[0][q * 4];
  #pragma unroll
  for (int j = 0; j < 16; ++j) {
    #pragma unroll
    for (int q = 0; q < 8; ++q) cur[q] = *(const float4*)&Xs[j + 1][q * 4];
    float a = bias;
    #pragma unroll
    for (int q = 0; q < 8; ++q) {
      a = fmaf(w0[q*4+0], prev[q].x, a); a = fmaf(w1[q*4+0], cur[q].x, a);
      a = fmaf(w0[q*4+1], prev[q].y, a); a = fmaf(w1[q*4+1], cur[q].y, a);
      a = fmaf(w0[q*4+2], prev[q].z, a); a = fmaf(w1[q*4+2], cur[q].z, a);
      a = fmaf(w0[q*4+3], prev[q].w, a); a = fmaf(w1[q*4+3], cur[q].w, a);
    }
    int tt = tt0 + j;
    size_t off = ((size_t)b * TBUF + tt) * RCH + r;
    if (tt < 3) { xbb[off] = 0; xlo[off] = 0; }
    else {
      unsigned short hn = f2bf(a);
      xbb[off] = hn;
      xlo[off] = f2bf(a - bf2f(hn));
    }
    #pragma unroll
    for (int q = 0; q < 8; ++q) prev[q] = cur[q];
  }
}

// ---------------- fused layer, adaptive M = NM*16 rows per block -------------
// 1024 thr = 16 waves. Separate Zs LDS region (no As aliasing) -> only TWO
// barriers per layer: (stage -> read) and (z-write -> res-read).
// 2-deep rotating weight prefetch: res loop always; conv loop for NM<=2
// (VGPR headroom). Rotating SCALARS only - never an array across a barrier
// (the r4/r8/r12/r17 spill pattern).
template<int NM>
__global__ __launch_bounds__(1024, 4) void layer_fused(
    const unsigned short* __restrict__ xbb_r, unsigned short* __restrict__ xbb_w,
    unsigned short* __restrict__ xlo,
    const unsigned short* __restrict__ Wb,   // [512][512] bf16
    const unsigned short* __restrict__ Wrb,  // [256][256] bf16
    const float* __restrict__ bF, const float* __restrict__ bG,
    const float* __restrict__ bR,
    int dd, int t_lo, float* __restrict__ fxs_i)
{
  __shared__ __align__(16) unsigned short As[NM * 16 * 520];  // 1040B rows
  __shared__ __align__(16) unsigned short Zs[NM * 16 * 264];  // 528B rows
  const int bid  = blockIdx.x;
  const int b    = bid & 15;
  const int tile = bid >> 4;
  const int tid  = threadIdx.x;
  const int w    = tid >> 6;          // 0..15
  const int lane = tid & 63;
  const int l15  = lane & 15;
  const int lk8  = (lane >> 4) << 3;
  const int rr0  = (lane >> 4) << 2;
  const int tt0  = t_lo + tile * (NM * 16);
  const unsigned short* xB = xbb_r + ((size_t)b << 18);

  // ---- stage A tile via global_load_lds: NM*16 rows x 512 k (NM rows/wave)
  {
    const int c   = lane;
    const int tap = c >> 5;
    const int cg  = (c & 31) << 3;
    #pragma unroll
    for (int it = 0; it < NM; ++it) {
      int r = it * 16 + w;
      int tt = tt0 + r - tap * dd;
      tt = min(max(tt, 0), 1023);
      __builtin_amdgcn_global_load_lds(
          (const __attribute__((address_space(1))) unsigned int*)
              (xB + ((size_t)tt << 8) + cg),
          (__attribute__((address_space(3))) unsigned int*)
              ((char*)As + r * 1040),
          16, 0, 0);
    }
  }

  // ---- preload weight chunks BEFORE the barrier (L2 latency overlaps drain)
  const unsigned short* wf0 = Wb + (size_t)(16 * w + l15) * 512 + lk8;
  const unsigned short* wg0 = wf0 + (size_t)256 * 512;
  const unsigned short* wr0 = Wrb + (size_t)(16 * w + l15) * 256 + lk8;
  uint4 nbf = *(const uint4*)(wf0);
  uint4 nbg = *(const uint4*)(wg0);
  uint4 nbf2, nbg2;
  if constexpr (NM <= 2) {
    nbf2 = *(const uint4*)(wf0 + 32);
    nbg2 = *(const uint4*)(wg0 + 32);
  }
  uint4 nr0 = *(const uint4*)(wr0);
  uint4 nr1 = *(const uint4*)(wr0 + 32);
  __syncthreads();   // B1: A-tile ready

  // ---- conv GEMM: per wave (NM*16)(M) x {16 f + 16 g}
  f32x4 accf[NM] = {};
  f32x4 accg[NM] = {};
  #pragma unroll 4
  for (int kc = 0; kc < 16; ++kc) {
    bf16x8 vf0 = __builtin_bit_cast(bf16x8, nbf);
    bf16x8 vg0 = __builtin_bit_cast(bf16x8, nbg);
    if constexpr (NM <= 2) {
      nbf = nbf2; nbg = nbg2;
      if (kc < 14) {
        nbf2 = *(const uint4*)(wf0 + (kc + 2) * 32);
        nbg2 = *(const uint4*)(wg0 + (kc + 2) * 32);
      }
    } else {
      if (kc < 15) {
        nbf = *(const uint4*)(wf0 + (kc + 1) * 32);
        nbg = *(const uint4*)(wg0 + (kc + 1) * 32);
      }
    }
    const int colb = (kc * 32 + lk8) * 2;
    bf16x8 a[NM];
    #pragma unroll
    for (int mf = 0; mf < NM; ++mf)
      a[mf] = *(const bf16x8*)((const char*)As + (mf * 16 + l15) * 1040 + colb);
    #pragma unroll
    for (int mf = 0; mf < NM; ++mf) {
      accf[mf] = __builtin_amdgcn_mfma_f32_16x16x32_bf16(a[mf], vf0, accf[mf], 0, 0, 0);
      accg[mf] = __builtin_amdgcn_mfma_f32_16x16x32_bf16(a[mf], vg0, accg[mf], 0, 0, 0);
    }
  }

  // ---- hi_old from A-tile LDS (tap-0 region; As is NOT overwritten now)
  const int col = 16 * w + l15;
  float hi_pre[NM][4];
  #pragma unroll
  for (int mf = 0; mf < NM; ++mf)
    #pragma unroll
    for (int j = 0; j < 4; ++j) {
      int row = mf * 16 + rr0 + j;
      hi_pre[mf][j] = bf2f(*(const unsigned short*)((const char*)As + row * 1040 + col * 2));
    }

  // ---- lo_old loads (latency hides under gate + barrier + res GEMM)
  unsigned short* xL = xlo + ((size_t)b << 18);
  float lo_pre[NM][4];
  #pragma unroll
  for (int mf = 0; mf < NM; ++mf)
    #pragma unroll
    for (int j = 0; j < 4; ++j) {
      int tt = min(tt0 + mf * 16 + rr0 + j, 1023);
      lo_pre[mf][j] = bf2f(xL[((size_t)tt << 8) + col]);
    }

  // ---- gate epilogue: z = tanh(f+bf) * sigmoid(g+bg) -> Zs (own region,
  //      no barrier needed before the write)
  const float bfv = bF[col];
  const float bgv = bG[col];
  #pragma unroll
  for (int mf = 0; mf < NM; ++mf)
    #pragma unroll
    for (int j = 0; j < 4; ++j) {
      int row = mf * 16 + rr0 + j;
      float pf = accf[mf][j] + bfv;
      float pg = accg[mf][j] + bgv;
      float e2 = __expf(2.f * pf);
      float th = 1.f - 2.f / (e2 + 1.f);
      float sg = 1.f / (1.f + __expf(-pg));
      *(unsigned short*)((char*)Zs + row * 528 + col * 2) = f2bf(th * sg);
    }
  __syncthreads();   // B2: z visible to all waves

  // ---- res GEMM: per wave (NM*16)(M) x 16(N), K=256, 2-deep rotating prefetch
  f32x4 acc[NM] = {};
  #pragma unroll 4
  for (int kc = 0; kc < 8; ++kc) {
    bf16x8 v0 = __builtin_bit_cast(bf16x8, nr0);
    nr0 = nr1;
    if (kc < 6) nr1 = *(const uint4*)(wr0 + (kc + 2) * 32);
    const int colb = (kc * 32 + lk8) * 2;
    bf16x8 a[NM];
    #pragma unroll
    for (int mf = 0; mf < NM; ++mf)
      a[mf] = *(const bf16x8*)((const char*)Zs + (mf * 16 + l15) * 528 + colb);
    #pragma unroll
    for (int mf = 0; mf < NM; ++mf)
      acc[mf] = __builtin_amdgcn_mfma_f32_16x16x32_bf16(a[mf], v0, acc[mf], 0, 0, 0);
  }

  // ---- residual epilogue: xn = (hi+lo) + fx; re-split to hi'/lo'; fx snapshot
  const float brv = bR[col];
  unsigned short* xBb = xbb_w + ((size_t)b << 18);
  #pragma unroll
  for (int mf = 0; mf < NM; ++mf)
    #pragma unroll
    for (int j = 0; j < 4; ++j) {
      int tt = tt0 + mf * 16 + rr0 + j;
      if (tt > 1023) continue;
      size_t off = ((size_t)tt << 8) + col;
      float fx = acc[mf][j] + brv;
      float xn = (hi_pre[mf][j] + lo_pre[mf][j]) + fx;
      unsigned short hn = f2bf(xn);
      xBb[off] = hn;
      xL[off]  = f2bf(xn - bf2f(hn));
      if (tt == 1023) fxs_i[(size_t)b * 256 + col] = fx;
    }
}

// ---------------- head ----------------
__global__ __launch_bounds__(128) void skip_partial(
    const float* __restrict__ fxs, const float* __restrict__ wskT,
    const float* __restrict__ b_skip, float* __restrict__ part)
{
  int i = blockIdx.x, b = blockIdx.y, s = threadIdx.x;
  __shared__ float fxsh[256];
  fxsh[s]       = fxs[((size_t)i * 16 + b) * 256 + s];
  fxsh[s + 128] = fxs[((size_t)i * 16 + b) * 256 + s + 128];
  __syncthreads();
  float a = b_skip[i * 128 + s];
  const float* wp = wskT + (size_t)i * 256 * 128 + s;
  #pragma unroll 4
  for (int c = 0; c < 256; c++)
    a = fmaf(wp[c * 128], fxsh[c], a);
  part[((size_t)i * 16 + b) * 128 + s] = a;
}

__global__ __launch_bounds__(128) void head2(
    const float* __restrict__ part, const float* __restrict__ w_o1,
    const float* __restrict__ b_o1, const float* __restrict__ w_o2,
    const float* __restrict__ b_o2, const float* __restrict__ w_lin,
    const float* __restrict__ b_lin, const float* __restrict__ Xex,
    float* __restrict__ out)
{
  int b = blockIdx.x, tid = threadIdx.x;
  __shared__ float sk[128];
  __shared__ float h1[64];
  __shared__ float hc[80];
  float a = 0.f;
  for (int i = 0; i < 32; i++) a += part[((size_t)i * 16 + b) * 128 + tid];
  sk[tid] = fmaxf(a, 0.f);
  __syncthreads();
  if (tid < 64) {
    float a1 = b_o1[tid];
    for (int s = 0; s < 128; s++) a1 = fmaf(w_o1[tid * 128 + s], sk[s], a1);
    h1[tid] = fmaxf(a1, 0.f);
  }
  __syncthreads();
  if (tid < 64) {
    float a2 = b_o2[tid];
    for (int j = 0; j < 64; j++) a2 = fmaf(w_o2[tid * 64 + j], h1[j], a2);
    hc[tid] = fmaxf(a2, 0.f);
  }
  if (tid >= 64 && tid < 80) hc[tid] = fmaxf(Xex[b * 16 + (tid - 64)], 0.f);
  __syncthreads();
  if (tid < 24) {
    float a3 = b_lin[tid];
    for (int j = 0; j < 80; j++) a3 = fmaf(w_lin[tid * 80 + j], hc[j], a3);
    out[b * 24 + tid] = a3;
  }
}

extern "C" void kernel_launch(void* const* d_in, const int* in_sizes, int n_in,
                              void* d_out, int out_size, void* d_ws, size_t ws_size,
                              hipStream_t stream)
{
  (void)in_sizes; (void)n_in; (void)out_size; (void)ws_size;
  const float* X     = (const float*)d_in[0];
  const float* Xex   = (const float*)d_in[1];
  const float* w_in  = (const float*)d_in[2];
  const float* b_in  = (const float*)d_in[3];
  const float* w_f   = (const float*)d_in[4];
  const float* b_f   = (const float*)d_in[5];
  const float* w_g   = (const float*)d_in[6];
  const float* b_g   = (const float*)d_in[7];
  const float* w_r   = (const float*)d_in[8];
  const float* b_r   = (const float*)d_in[9];
  const float* w_s   = (const float*)d_in[10];
  const float* b_s   = (const float*)d_in[11];
  const float* w_o1  = (const float*)d_in[12];
  const float* b_o1  = (const float*)d_in[13];
  const float* w_o2  = (const float*)d_in[14];
  const float* b_o2  = (const float*)d_in[15];
  const float* w_lin = (const float*)d_in[16];
  const float* b_lin = (const float*)d_in[17];

  float* ws   = (float*)d_ws;
  float* wskT = ws;                        // 1,048,576 f
  float* fxs  = wskT + 1048576;            // 131,072 f
  float* part = fxs  + 131072;             // 65,536 f
  float* w2   = part + 65536;              // 16,384 f
  unsigned short* Wb   = (unsigned short*)(w2 + 16384);    // 8,388,608 us
  unsigned short* Wrb  = Wb   + 8388608;   // 2,097,152 us
  unsigned short* xbbA = Wrb  + 2097152;   // 4,194,304 us
  unsigned short* xbbB = xbbA + 4194304;   // 4,194,304 us
  unsigned short* xlo  = xbbB + 4194304;   // 4,194,304 us

  prep<<<22592, 256, 0, stream>>>(w_f, w_g, w_r, w_s, w_in, Wb, Wrb, wskT, w2);
  in_conv<<<1024, 256, 0, stream>>>(X, w2, b_in, xbbA, xlo);

  // suffix-window sizes: w[i] = w[i+1] + 2^(i%8), w[32] = 1
  static const int wI[33] = {1021,1020,1018,1014,1006,990,958,894,
                             766,765,763,759,751,735,703,639,
                             511,510,508,504,496,480,448,384,
                             256,255,253,249,241,225,193,129,1};
  for (int i = 0; i < 32; i++) {
    int dd    = 1 << (i & 7);
    int Wout  = wI[i + 1];
    int t_lo  = TBUF - Wout;
    unsigned short* xin  = (i & 1) ? xbbB : xbbA;
    unsigned short* xout = (i & 1) ? xbbA : xbbB;
    const unsigned short* WbL  = Wb  + (size_t)i * 262144;
    const unsigned short* WrbL = Wrb + (size_t)i * 65536;
    const float* bFi = b_f + i * 256;
    const float* bGi = b_g + i * 256;
    const float* bRi = b_r + i * 256;
    float* fxi = fxs + (size_t)i * 4096;
    // NM = ceil(W/256): smallest per-block work with grid <= 256 blocks.
    int NM = (Wout + 255) >> 8;
    int tiles = (Wout + NM * 16 - 1) / (NM * 16);
    switch (NM) {
      case 4:
        layer_fused<4><<<tiles * 16, 1024, 0, stream>>>(
            xin, xout, xlo, WbL, WrbL, bFi, bGi, bRi, dd, t_lo, fxi);
        break;
      case 3:
        layer_fused<3><<<tiles * 16, 1024, 0, stream>>>(
            xin, xout, xlo, WbL, WrbL, bFi, bGi, bRi, dd, t_lo, fxi);
        break;
      case 2:
        layer_fused<2><<<tiles * 16, 1024, 0, stream>>>(
            xin, xout, xlo, WbL, WrbL, bFi, bGi, bRi, dd, t_lo, fxi);
        break;
      default:
        layer_fused<1><<<tiles * 16, 1024, 0, stream>>>(
            xin, xout, xlo, WbL, WrbL, bFi, bGi, bRi, dd, t_lo, fxi);
        break;
    }
  }
  skip_partial<<<dim3(32, 16), 128, 0, stream>>>(fxs, wskT, b_s, part);
  head2<<<16, 128, 0, stream>>>(part, w_o1, b_o1, w_o2, b_o2, w_lin, b_lin, Xex, (float*)d_out);
}

// Round 20
// 856.344 us; speedup vs baseline: 1.0999x; 1.0075x over previous
//
#include <hip/hip_runtime.h>
#include <cmath>

#define TBUF 1024
#define RCH  256

typedef __bf16 bf16x8 __attribute__((ext_vector_type(8)));
typedef float  f32x4  __attribute__((ext_vector_type(4)));

__device__ inline unsigned short f2bf(float f) {
  unsigned u = __builtin_bit_cast(unsigned, f);
  u += 0x7FFFu + ((u >> 16) & 1u);
  return (unsigned short)(u >> 16);
}
__device__ inline float bf2f(unsigned short h) {
  unsigned u = ((unsigned)h) << 16;
  return __builtin_bit_cast(float, u);
}

// ---------------- merged weight transforms (one dispatch) ----------------
__global__ __launch_bounds__(256) void prep(
    const float* __restrict__ wf, const float* __restrict__ wg,
    const float* __restrict__ wr, const float* __restrict__ wsk,
    const float* __restrict__ w_in,
    unsigned short* __restrict__ Wb, unsigned short* __restrict__ Wrb,
    float* __restrict__ wskT, float* __restrict__ w2)
{
  const int bid = blockIdx.x;
  const int tid = threadIdx.x;
  if (bid < 16384) {
    int idx = bid * 256 + tid;
    int c  = idx & 255;
    int op = (idx >> 8) & 511;
    int i  = idx >> 17;
    int o  = op & 255;
    const float* src = (op < 256) ? wf : wg;
    const float2 v = *(const float2*)&src[(((size_t)i * 256 + o) * 256 + c) << 1];
    unsigned short* dst = Wb + ((size_t)i * 512 + op) * 512;
    dst[c]       = f2bf(v.y);   // current tap (k=1)
    dst[256 + c] = f2bf(v.x);   // previous tap (k=0)
  } else if (bid < 18432) {
    int idx = (bid - 16384) * 256 + tid;
    float4 v = ((const float4*)wr)[idx];
    uint2 o;
    o.x = (unsigned)f2bf(v.x) | ((unsigned)f2bf(v.y) << 16);
    o.y = (unsigned)f2bf(v.z) | ((unsigned)f2bf(v.w) << 16);
    ((uint2*)Wrb)[idx] = o;
  } else if (bid < 22528) {
    int idx = (bid - 18432) * 256 + tid;
    int s = idx & 127;
    int c = (idx >> 7) & 255;
    int i = idx >> 15;
    wskT[idx] = wsk[(i * 128 + s) * 256 + c];
  } else {
    int idx = (bid - 22528) * 256 + tid;
    int r = idx & 255;
    int fk = idx >> 8;
    int f = fk & 31, k = fk >> 5;
    w2[idx] = w_in[r * 64 + f * 2 + k];
  }
}

// ---------------- input conv (F=32 -> R=256, K=2, d=1) ----------------
__global__ __launch_bounds__(256) void in_conv(
    const float* __restrict__ X, const float* __restrict__ w2,
    const float* __restrict__ b_in, unsigned short* __restrict__ xbb,
    unsigned short* __restrict__ xlo)
{
  const int bid   = blockIdx.x;
  const int b     = bid & 15;
  const int chunk = bid >> 4;
  const int r     = threadIdx.x;
  __shared__ float Xs[17][32];
  const int tt0 = chunk << 4;
  const int t0  = tt0 + 1024;
  for (int idx = r; idx < 17 * 32; idx += 256) {
    int row = idx >> 5, f = idx & 31;
    Xs[row][f] = X[((size_t)b * 2048 + (t0 - 1 + row)) * 32 + f];
  }
  __syncthreads();
  float w0[32], w1[32];
  #pragma unroll
  for (int f = 0; f < 32; ++f) {
    w0[f] = w2[f * 256 + r];
    w1[f] = w2[(32 + f) * 256 + r];
  }
  const float bias = b_in[r];
  float4 prev[8], cur[8];
  #pragma unroll
  for (int q = 0; q < 8; ++q) prev[q] = *(const float4*)&Xs[0][q * 4];
  #pragma unroll
  for (int j = 0; j < 16; ++j) {
    #pragma unroll
    for (int q = 0; q < 8; ++q) cur[q] = *(const float4*)&Xs[j + 1][q * 4];
    float a = bias;
    #pragma unroll
    for (int q = 0; q < 8; ++q) {
      a = fmaf(w0[q*4+0], prev[q].x, a); a = fmaf(w1[q*4+0], cur[q].x, a);
      a = fmaf(w0[q*4+1], prev[q].y, a); a = fmaf(w1[q*4+1], cur[q].y, a);
      a = fmaf(w0[q*4+2], prev[q].z, a); a = fmaf(w1[q*4+2], cur[q].z, a);
      a = fmaf(w0[q*4+3], prev[q].w, a); a = fmaf(w1[q*4+3], cur[q].w, a);
    }
    int tt = tt0 + j;
    size_t off = ((size_t)b * TBUF + tt) * RCH + r;
    if (tt < 3) { xbb[off] = 0; xlo[off] = 0; }
    else {
      unsigned short hn = f2bf(a);
      xbb[off] = hn;
      xlo[off] = f2bf(a - bf2f(hn));
    }
    #pragma unroll
    for (int q = 0; q < 8; ++q) prev[q] = cur[q];
  }
}

// ---------------- fused layer, adaptive M = NM*16 rows per block -------------
// 1024 thr = 16 waves. Separate Zs LDS region -> only TWO barriers per layer.
// 2-deep rotating weight prefetch in BOTH GEMM loops, all NM (rotating
// SCALARS only - never an array across a barrier: r4/r8/r12/r17 spill pattern).
template<int NM>
__global__ __launch_bounds__(1024, 4) void layer_fused(
    const unsigned short* __restrict__ xbb_r, unsigned short* __restrict__ xbb_w,
    unsigned short* __restrict__ xlo,
    const unsigned short* __restrict__ Wb,   // [512][512] bf16
    const unsigned short* __restrict__ Wrb,  // [256][256] bf16
    const float* __restrict__ bF, const float* __restrict__ bG,
    const float* __restrict__ bR,
    int dd, int t_lo, float* __restrict__ fxs_i)
{
  __shared__ __align__(16) unsigned short As[NM * 16 * 520];  // 1040B rows
  __shared__ __align__(16) unsigned short Zs[NM * 16 * 264];  // 528B rows
  const int bid  = blockIdx.x;
  const int b    = bid & 15;
  const int tile = bid >> 4;
  const int tid  = threadIdx.x;
  const int w    = tid >> 6;          // 0..15
  const int lane = tid & 63;
  const int l15  = lane & 15;
  const int lk8  = (lane >> 4) << 3;
  const int rr0  = (lane >> 4) << 2;
  const int tt0  = t_lo + tile * (NM * 16);
  const unsigned short* xB = xbb_r + ((size_t)b << 18);

  // ---- stage A tile via global_load_lds: NM*16 rows x 512 k (NM rows/wave)
  {
    const int c   = lane;
    const int tap = c >> 5;
    const int cg  = (c & 31) << 3;
    #pragma unroll
    for (int it = 0; it < NM; ++it) {
      int r = it * 16 + w;
      int tt = tt0 + r - tap * dd;
      tt = min(max(tt, 0), 1023);
      __builtin_amdgcn_global_load_lds(
          (const __attribute__((address_space(1))) unsigned int*)
              (xB + ((size_t)tt << 8) + cg),
          (__attribute__((address_space(3))) unsigned int*)
              ((char*)As + r * 1040),
          16, 0, 0);
    }
  }

  // ---- preload weight chunks BEFORE the barrier (L2 latency overlaps drain)
  const unsigned short* wf0 = Wb + (size_t)(16 * w + l15) * 512 + lk8;
  const unsigned short* wg0 = wf0 + (size_t)256 * 512;
  const unsigned short* wr0 = Wrb + (size_t)(16 * w + l15) * 256 + lk8;
  uint4 nbf  = *(const uint4*)(wf0);
  uint4 nbg  = *(const uint4*)(wg0);
  uint4 nbf2 = *(const uint4*)(wf0 + 32);
  uint4 nbg2 = *(const uint4*)(wg0 + 32);
  uint4 nr0 = *(const uint4*)(wr0);
  uint4 nr1 = *(const uint4*)(wr0 + 32);
  __syncthreads();   // B1: A-tile ready

  // ---- conv GEMM: per wave (NM*16)(M) x {16 f + 16 g}, 2-deep rotation
  f32x4 accf[NM] = {};
  f32x4 accg[NM] = {};
  #pragma unroll 4
  for (int kc = 0; kc < 16; ++kc) {
    bf16x8 vf0 = __builtin_bit_cast(bf16x8, nbf);
    bf16x8 vg0 = __builtin_bit_cast(bf16x8, nbg);
    nbf = nbf2; nbg = nbg2;
    if (kc < 14) {
      nbf2 = *(const uint4*)(wf0 + (kc + 2) * 32);
      nbg2 = *(const uint4*)(wg0 + (kc + 2) * 32);
    }
    const int colb = (kc * 32 + lk8) * 2;
    bf16x8 a[NM];
    #pragma unroll
    for (int mf = 0; mf < NM; ++mf)
      a[mf] = *(const bf16x8*)((const char*)As + (mf * 16 + l15) * 1040 + colb);
    #pragma unroll
    for (int mf = 0; mf < NM; ++mf) {
      accf[mf] = __builtin_amdgcn_mfma_f32_16x16x32_bf16(a[mf], vf0, accf[mf], 0, 0, 0);
      accg[mf] = __builtin_amdgcn_mfma_f32_16x16x32_bf16(a[mf], vg0, accg[mf], 0, 0, 0);
    }
  }

  // ---- hi_old from A-tile LDS (tap-0 region; As is NOT overwritten now)
  const int col = 16 * w + l15;
  float hi_pre[NM][4];
  #pragma unroll
  for (int mf = 0; mf < NM; ++mf)
    #pragma unroll
    for (int j = 0; j < 4; ++j) {
      int row = mf * 16 + rr0 + j;
      hi_pre[mf][j] = bf2f(*(const unsigned short*)((const char*)As + row * 1040 + col * 2));
    }

  // ---- lo_old loads (latency hides under gate + barrier + res GEMM)
  unsigned short* xL = xlo + ((size_t)b << 18);
  float lo_pre[NM][4];
  #pragma unroll
  for (int mf = 0; mf < NM; ++mf)
    #pragma unroll
    for (int j = 0; j < 4; ++j) {
      int tt = min(tt0 + mf * 16 + rr0 + j, 1023);
      lo_pre[mf][j] = bf2f(xL[((size_t)tt << 8) + col]);
    }

  // ---- gate epilogue: z = tanh(f+bf) * sigmoid(g+bg) -> Zs (own region)
  const float bfv = bF[col];
  const float bgv = bG[col];
  #pragma unroll
  for (int mf = 0; mf < NM; ++mf)
    #pragma unroll
    for (int j = 0; j < 4; ++j) {
      int row = mf * 16 + rr0 + j;
      float pf = accf[mf][j] + bfv;
      float pg = accg[mf][j] + bgv;
      float e2 = __expf(2.f * pf);
      float th = 1.f - 2.f / (e2 + 1.f);
      float sg = 1.f / (1.f + __expf(-pg));
      *(unsigned short*)((char*)Zs + row * 528 + col * 2) = f2bf(th * sg);
    }
  __syncthreads();   // B2: z visible to all waves

  // ---- res GEMM: per wave (NM*16)(M) x 16(N), K=256, 2-deep rotation
  f32x4 acc[NM] = {};
  #pragma unroll 4
  for (int kc = 0; kc < 8; ++kc) {
    bf16x8 v0 = __builtin_bit_cast(bf16x8, nr0);
    nr0 = nr1;
    if (kc < 6) nr1 = *(const uint4*)(wr0 + (kc + 2) * 32);
    const int colb = (kc * 32 + lk8) * 2;
    bf16x8 a[NM];
    #pragma unroll
    for (int mf = 0; mf < NM; ++mf)
      a[mf] = *(const bf16x8*)((const char*)Zs + (mf * 16 + l15) * 528 + colb);
    #pragma unroll
    for (int mf = 0; mf < NM; ++mf)
      acc[mf] = __builtin_amdgcn_mfma_f32_16x16x32_bf16(a[mf], v0, acc[mf], 0, 0, 0);
  }

  // ---- residual epilogue: xn = (hi+lo) + fx; re-split to hi'/lo'; fx snapshot
  const float brv = bR[col];
  unsigned short* xBb = xbb_w + ((size_t)b << 18);
  #pragma unroll
  for (int mf = 0; mf < NM; ++mf)
    #pragma unroll
    for (int j = 0; j < 4; ++j) {
      int tt = tt0 + mf * 16 + rr0 + j;
      if (tt > 1023) continue;
      size_t off = ((size_t)tt << 8) + col;
      float fx = acc[mf][j] + brv;
      float xn = (hi_pre[mf][j] + lo_pre[mf][j]) + fx;
      unsigned short hn = f2bf(xn);
      xBb[off] = hn;
      xL[off]  = f2bf(xn - bf2f(hn));
      if (tt == 1023) fxs_i[(size_t)b * 256 + col] = fx;
    }
}

// ---------------- head ----------------
__global__ __launch_bounds__(128) void skip_partial(
    const float* __restrict__ fxs, const float* __restrict__ wskT,
    const float* __restrict__ b_skip, float* __restrict__ part)
{
  int i = blockIdx.x, b = blockIdx.y, s = threadIdx.x;
  __shared__ float fxsh[256];
  fxsh[s]       = fxs[((size_t)i * 16 + b) * 256 + s];
  fxsh[s + 128] = fxs[((size_t)i * 16 + b) * 256 + s + 128];
  __syncthreads();
  float a = b_skip[i * 128 + s];
  const float* wp = wskT + (size_t)i * 256 * 128 + s;
  #pragma unroll 4
  for (int c = 0; c < 256; c++)
    a = fmaf(wp[c * 128], fxsh[c], a);
  part[((size_t)i * 16 + b) * 128 + s] = a;
}

__global__ __launch_bounds__(128) void head2(
    const float* __restrict__ part, const float* __restrict__ w_o1,
    const float* __restrict__ b_o1, const float* __restrict__ w_o2,
    const float* __restrict__ b_o2, const float* __restrict__ w_lin,
    const float* __restrict__ b_lin, const float* __restrict__ Xex,
    float* __restrict__ out)
{
  int b = blockIdx.x, tid = threadIdx.x;
  __shared__ float sk[128];
  __shared__ float h1[64];
  __shared__ float hc[80];
  float a = 0.f;
  for (int i = 0; i < 32; i++) a += part[((size_t)i * 16 + b) * 128 + tid];
  sk[tid] = fmaxf(a, 0.f);
  __syncthreads();
  if (tid < 64) {
    float a1 = b_o1[tid];
    for (int s = 0; s < 128; s++) a1 = fmaf(w_o1[tid * 128 + s], sk[s], a1);
    h1[tid] = fmaxf(a1, 0.f);
  }
  __syncthreads();
  if (tid < 64) {
    float a2 = b_o2[tid];
    for (int j = 0; j < 64; j++) a2 = fmaf(w_o2[tid * 64 + j], h1[j], a2);
    hc[tid] = fmaxf(a2, 0.f);
  }
  if (tid >= 64 && tid < 80) hc[tid] = fmaxf(Xex[b * 16 + (tid - 64)], 0.f);
  __syncthreads();
  if (tid < 24) {
    float a3 = b_lin[tid];
    for (int j = 0; j < 80; j++) a3 = fmaf(w_lin[tid * 80 + j], hc[j], a3);
    out[b * 24 + tid] = a3;
  }
}

extern "C" void kernel_launch(void* const* d_in, const int* in_sizes, int n_in,
                              void* d_out, int out_size, void* d_ws, size_t ws_size,
                              hipStream_t stream)
{
  (void)in_sizes; (void)n_in; (void)out_size; (void)ws_size;
  const float* X     = (const float*)d_in[0];
  const float* Xex   = (const float*)d_in[1];
  const float* w_in  = (const float*)d_in[2];
  const float* b_in  = (const float*)d_in[3];
  const float* w_f   = (const float*)d_in[4];
  const float* b_f   = (const float*)d_in[5];
  const float* w_g   = (const float*)d_in[6];
  const float* b_g   = (const float*)d_in[7];
  const float* w_r   = (const float*)d_in[8];
  const float* b_r   = (const float*)d_in[9];
  const float* w_s   = (const float*)d_in[10];
  const float* b_s   = (const float*)d_in[11];
  const float* w_o1  = (const float*)d_in[12];
  const float* b_o1  = (const float*)d_in[13];
  const float* w_o2  = (const float*)d_in[14];
  const float* b_o2  = (const float*)d_in[15];
  const float* w_lin = (const float*)d_in[16];
  const float* b_lin = (const float*)d_in[17];

  float* ws   = (float*)d_ws;
  float* wskT = ws;                        // 1,048,576 f
  float* fxs  = wskT + 1048576;            // 131,072 f
  float* part = fxs  + 131072;             // 65,536 f
  float* w2   = part + 65536;              // 16,384 f
  unsigned short* Wb   = (unsigned short*)(w2 + 16384);    // 8,388,608 us
  unsigned short* Wrb  = Wb   + 8388608;   // 2,097,152 us
  unsigned short* xbbA = Wrb  + 2097152;   // 4,194,304 us
  unsigned short* xbbB = xbbA + 4194304;   // 4,194,304 us
  unsigned short* xlo  = xbbB + 4194304;   // 4,194,304 us

  prep<<<22592, 256, 0, stream>>>(w_f, w_g, w_r, w_s, w_in, Wb, Wrb, wskT, w2);
  in_conv<<<1024, 256, 0, stream>>>(X, w2, b_in, xbbA, xlo);

  // suffix-window sizes: w[i] = w[i+1] + 2^(i%8), w[32] = 1
  static const int wI[33] = {1021,1020,1018,1014,1006,990,958,894,
                             766,765,763,759,751,735,703,639,
                             511,510,508,504,496,480,448,384,
                             256,255,253,249,241,225,193,129,1};
  for (int i = 0; i < 32; i++) {
    int dd    = 1 << (i & 7);
    int Wout  = wI[i + 1];
    int t_lo  = TBUF - Wout;
    unsigned short* xin  = (i & 1) ? xbbB : xbbA;
    unsigned short* xout = (i & 1) ? xbbA : xbbB;
    const unsigned short* WbL  = Wb  + (size_t)i * 262144;
    const unsigned short* WrbL = Wrb + (size_t)i * 65536;
    const float* bFi = b_f + i * 256;
    const float* bGi = b_g + i * 256;
    const float* bRi = b_r + i * 256;
    float* fxi = fxs + (size_t)i * 4096;
    // NM = ceil(W/256): smallest per-block work with grid <= 256 blocks.
    int NM = (Wout + 255) >> 8;
    int tiles = (Wout + NM * 16 - 1) / (NM * 16);
    switch (NM) {
      case 4:
        layer_fused<4><<<tiles * 16, 1024, 0, stream>>>(
            xin, xout, xlo, WbL, WrbL, bFi, bGi, bRi, dd, t_lo, fxi);
        break;
      case 3:
        layer_fused<3><<<tiles * 16, 1024, 0, stream>>>(
            xin, xout, xlo, WbL, WrbL, bFi, bGi, bRi, dd, t_lo, fxi);
        break;
      case 2:
        layer_fused<2><<<tiles * 16, 1024, 0, stream>>>(
            xin, xout, xlo, WbL, WrbL, bFi, bGi, bRi, dd, t_lo, fxi);
        break;
      default:
        layer_fused<1><<<tiles * 16, 1024, 0, stream>>>(
            xin, xout, xlo, WbL, WrbL, bFi, bGi, bRi, dd, t_lo, fxi);
        break;
    }
  }
  skip_partial<<<dim3(32, 16), 128, 0, stream>>>(fxs, wskT, b_s, part);
  head2<<<16, 128, 0, stream>>>(part, w_o1, b_o1, w_o2, b_o2, w_lin, b_lin, Xex, (float*)d_out);
}